// Round 4
// baseline (146.801 us; speedup 1.0000x reference)
//
#include <hip/hip_runtime.h>
#include <hip/hip_bf16.h>
#include <cstdint>
#include <cstddef>

typedef __attribute__((ext_vector_type(8))) short bf16x8;
typedef __attribute__((ext_vector_type(4))) float f32x4;

__device__ __forceinline__ unsigned short f2bf(float f) {
  union { float f; unsigned u; } v; v.f = f;
  unsigned r = v.u + 0x7FFFu + ((v.u >> 16) & 1u);
  return (unsigned short)(r >> 16);
}

__device__ __forceinline__ void gload_lds16(const void* g, void* l) {
  __builtin_amdgcn_global_load_lds(
      (const __attribute__((address_space(1))) unsigned int*)g,
      (__attribute__((address_space(3))) unsigned int*)l, 16, 0, 0);
}

// ---------------------------------------------------------------------------
// K01 fused: blocks [0,256): W transpose->bf16 Wt[1024cls][1024k] (pad 0,
//            row 1000 SKIPPED — reserved for s). blocks [256,768): per-row
//            rnorm, x->bf16, s += xn (atomics). The LAST norm block (atomic
//            counter) converts s -> bf16 into Wt row 1000, so the GEMM
//            computes dot(x_row, s) as "class 1000" for free.
// ---------------------------------------------------------------------------
__global__ __launch_bounds__(256) void k01_prep(const float* __restrict__ W,
                                                unsigned short* __restrict__ Wt,
                                                const float* __restrict__ x,
                                                unsigned short* __restrict__ xbf,
                                                float* __restrict__ rnorm,
                                                float* __restrict__ s,
                                                int* __restrict__ cnt2) {
  __shared__ __align__(16) char sm[16640];
  __shared__ int lf;
  int tid = threadIdx.x;
  if (blockIdx.x < 256) {
    float (*tile)[65] = (float(*)[65])sm;
    int k0 = (blockIdx.x & 15) * 64;
    int c0 = (blockIdx.x >> 4) * 64;
    int tx = tid & 63;
    int ty = tid >> 6;
#pragma unroll
    for (int i = 0; i < 16; ++i) {
      int r = i * 4 + ty;
      int c = c0 + tx;
      tile[r][tx] = (c < 1000) ? W[(size_t)(k0 + r) * 1000 + c] : 0.f;
    }
    __syncthreads();
#pragma unroll
    for (int i = 0; i < 16; ++i) {
      int ct = i * 4 + ty;
      int cg = c0 + ct;
      if (cg != 1000)  // row 1000 owned by the s-writer below
        Wt[(size_t)cg * 1024 + (k0 + tx)] = f2bf(tile[tx][ct]);
    }
    return;
  }
  float (*sblk)[1024] = (float(*)[1024])sm;
  int bid = blockIdx.x - 256;
  int wid = tid >> 6, lane = tid & 63;
  float4 sacc[4];
#pragma unroll
  for (int j = 0; j < 4; ++j) sacc[j] = make_float4(0.f, 0.f, 0.f, 0.f);
#pragma unroll
  for (int r = 0; r < 4; ++r) {
    int row = bid * 16 + wid * 4 + r;
    const float4* xr = (const float4*)(x + (size_t)row * 1024);
    float4 v[4];
    float ss = 0.f;
#pragma unroll
    for (int j = 0; j < 4; ++j) {
      v[j] = xr[lane + j * 64];
      ss += v[j].x * v[j].x + v[j].y * v[j].y + v[j].z * v[j].z + v[j].w * v[j].w;
    }
#pragma unroll
    for (int m = 1; m < 64; m <<= 1) ss += __shfl_xor(ss, m);
    float rn = 1.f / fmaxf(sqrtf(ss), 1e-8f);
    if (lane == 0) rnorm[row] = rn;
#pragma unroll
    for (int j = 0; j < 4; ++j) {
      ushort4 hv;
      hv.x = f2bf(v[j].x); hv.y = f2bf(v[j].y);
      hv.z = f2bf(v[j].z); hv.w = f2bf(v[j].w);
      ((ushort4*)(xbf + (size_t)row * 1024))[lane + j * 64] = hv;
      sacc[j].x += v[j].x * rn; sacc[j].y += v[j].y * rn;
      sacc[j].z += v[j].z * rn; sacc[j].w += v[j].w * rn;
    }
  }
#pragma unroll
  for (int j = 0; j < 4; ++j) ((float4*)sblk[wid])[j * 64 + lane] = sacc[j];
  __syncthreads();
  for (int d = tid; d < 1024; d += 256) {
    float t = sblk[0][d] + sblk[1][d] + sblk[2][d] + sblk[3][d];
    atomicAdd(&s[d], t);
  }
  // last norm block writes bf16(s) into Wt row 1000 (device-scope protocol)
  __threadfence();
  __syncthreads();
  if (tid == 0) lf = (atomicAdd(cnt2, 1) == 511) ? 1 : 0;
  __syncthreads();
  if (lf) {
    __threadfence();
    float4 sv4 = ((const float4*)s)[tid];  // 256 thr x 4 = 1024
    ushort4 h;
    h.x = f2bf(sv4.x); h.y = f2bf(sv4.y);
    h.z = f2bf(sv4.z); h.w = f2bf(sv4.w);
    ((ushort4*)(Wt + (size_t)1000 * 1024))[tid] = h;
  }
}

// ---------------------------------------------------------------------------
// K3: bf16 MFMA GEMM (cls x rows) + fused softmax partials + split-K fixup.
// Block = 128 cls x 256 rows, BK=64, 16 K-tiles; grid 256 = 8 cls-chunks
// (XCD-aligned) x 32 row-blocks; 512 thr (8 waves, 2c x 4r, wave = 64x64).
// Tri-buffered LDS, depth-2 prefetch, counted vmcnt(6) (vmcnt(0) on the
// peeled last tile), one s_barrier/iter, XOR-swizzle (inverse on global src).
// Class 1000 = dot(x_row, s): extracted to pd, masked from softmax stats.
// The 8th-finishing block per row-block merges partials -> out (K4 folded).
// ---------------------------------------------------------------------------
#define LDSBUF 49152

__global__ __launch_bounds__(512) void k3_gemm(const unsigned short* __restrict__ xbf,
                                               const unsigned short* __restrict__ wt,
                                               const float* __restrict__ bias,
                                               const float* __restrict__ rnorm,
                                               float* __restrict__ pm,
                                               float* __restrict__ pz,
                                               float* __restrict__ ps,
                                               float* __restrict__ pd,
                                               int* __restrict__ cnt,
                                               float* __restrict__ out) {
  __shared__ __align__(16) char lds[147456];  // 3 bufs x (A 16KB + B 32KB)
  __shared__ int lastflag;

  int tid = threadIdx.x;
  int lane = tid & 63;
  int wid = tid >> 6;
  int wc = wid & 1;   // cls half (64)
  int wr = wid >> 1;  // row quarter (64)
  int cb = blockIdx.x & 7;   // cls chunk -> XCD round-robin
  int rb = blockIdx.x >> 3;  // 0..31
  int C0 = cb * 128;
  int R0 = rb * 256;

  // bias (+pad mask) folded into acc init. C/D map: row(cls)=(lane>>4)*4+q,
  // col(xrow)=lane&15. cls 1000 (the s-column) inits to 0.
  float bv[4][4];
#pragma unroll
  for (int mf = 0; mf < 4; ++mf)
#pragma unroll
    for (int q = 0; q < 4; ++q) {
      int cls_g = C0 + wc * 64 + mf * 16 + (lane >> 4) * 4 + q;
      bv[mf][q] = (cls_g < 1000) ? bias[cls_g] : ((cls_g == 1000) ? 0.f : -1e30f);
    }
  f32x4 acc[4][4];
#pragma unroll
  for (int mf = 0; mf < 4; ++mf)
#pragma unroll
    for (int nf = 0; nf < 4; ++nf)
#pragma unroll
      for (int q = 0; q < 4; ++q) acc[mf][nf][q] = bv[mf][q];

  const char* gA = (const char*)(wt + (size_t)C0 * 1024);
  const char* gB = (const char*)(xbf + (size_t)R0 * 1024);
  int grow = lane >> 3;
  int gswz = ((lane & 7) ^ grow) << 4;  // inverse-swizzled k-byte src

#define STA(kt, b, r)                                                          \
  gload_lds16(gA + (size_t)((r) * 64 + wid * 8 + grow) * 2048 + (kt) * 128 +   \
                  gswz,                                                        \
              lds + (b) * LDSBUF + (r) * 8192 + wid * 1024)
#define STB(kt, b, r)                                                          \
  gload_lds16(gB + (size_t)((r) * 64 + wid * 8 + grow) * 2048 + (kt) * 128 +   \
                  gswz,                                                        \
              lds + (b) * LDSBUF + 16384 + (r) * 8192 + wid * 1024)

  // prologue: tiles 0 and 1 (oldest-first for vmcnt counting)
  STA(0, 0, 0); STA(0, 0, 1); STB(0, 0, 0); STB(0, 0, 1); STB(0, 0, 2); STB(0, 0, 3);
  STA(1, 1, 0); STA(1, 1, 1); STB(1, 1, 0); STB(1, 1, 1); STB(1, 1, 2); STB(1, 1, 3);

  int rsw = (lane & 7) << 4;
  int kcol = (lane >> 4) * 16;

  for (int t = 0; t < 16; ++t) {
    if (t == 15) {
      asm volatile("s_waitcnt vmcnt(0)" ::: "memory");  // last tile: drain
    } else {
      asm volatile("s_waitcnt vmcnt(6)" ::: "memory");
    }
    __builtin_amdgcn_s_barrier();
    asm volatile("" ::: "memory");
    const char* A = lds + (t % 3) * LDSBUF;
    const char* B = A + 16384;
    int nt = t + 2;
    int nb = nt % 3;
    bool pf = nt < 16;

    if (pf) { STA(nt, nb, 0); STA(nt, nb, 1); }
    bf16x8 a[4][2];
#pragma unroll
    for (int mf = 0; mf < 4; ++mf)
#pragma unroll
      for (int ks = 0; ks < 2; ++ks)
        a[mf][ks] = *(const bf16x8*)(A + (wc * 64 + mf * 16 + (lane & 15)) * 128 +
                                     ((ks * 64 + kcol) ^ rsw));
    {
      bf16x8 b0[2];
#pragma unroll
      for (int ks = 0; ks < 2; ++ks)
        b0[ks] = *(const bf16x8*)(B + (wr * 64 + 0 * 16 + (lane & 15)) * 128 +
                                  ((ks * 64 + kcol) ^ rsw));
      __builtin_amdgcn_s_setprio(1);
#pragma unroll
      for (int ks = 0; ks < 2; ++ks)
#pragma unroll
        for (int mf = 0; mf < 4; ++mf)
          acc[mf][0] = __builtin_amdgcn_mfma_f32_16x16x32_bf16(a[mf][ks], b0[ks],
                                                               acc[mf][0], 0, 0, 0);
      __builtin_amdgcn_s_setprio(0);
    }
    if (pf) { STB(nt, nb, 0); STB(nt, nb, 1); }
    {
      bf16x8 b1[2];
#pragma unroll
      for (int ks = 0; ks < 2; ++ks)
        b1[ks] = *(const bf16x8*)(B + (wr * 64 + 1 * 16 + (lane & 15)) * 128 +
                                  ((ks * 64 + kcol) ^ rsw));
      __builtin_amdgcn_s_setprio(1);
#pragma unroll
      for (int ks = 0; ks < 2; ++ks)
#pragma unroll
        for (int mf = 0; mf < 4; ++mf)
          acc[mf][1] = __builtin_amdgcn_mfma_f32_16x16x32_bf16(a[mf][ks], b1[ks],
                                                               acc[mf][1], 0, 0, 0);
      __builtin_amdgcn_s_setprio(0);
    }
    if (pf) { STB(nt, nb, 2); STB(nt, nb, 3); }
    {
      bf16x8 b2[2];
#pragma unroll
      for (int ks = 0; ks < 2; ++ks)
        b2[ks] = *(const bf16x8*)(B + (wr * 64 + 2 * 16 + (lane & 15)) * 128 +
                                  ((ks * 64 + kcol) ^ rsw));
      __builtin_amdgcn_s_setprio(1);
#pragma unroll
      for (int ks = 0; ks < 2; ++ks)
#pragma unroll
        for (int mf = 0; mf < 4; ++mf)
          acc[mf][2] = __builtin_amdgcn_mfma_f32_16x16x32_bf16(a[mf][ks], b2[ks],
                                                               acc[mf][2], 0, 0, 0);
      __builtin_amdgcn_s_setprio(0);
    }
    {
      bf16x8 b3[2];
#pragma unroll
      for (int ks = 0; ks < 2; ++ks)
        b3[ks] = *(const bf16x8*)(B + (wr * 64 + 3 * 16 + (lane & 15)) * 128 +
                                  ((ks * 64 + kcol) ^ rsw));
      __builtin_amdgcn_s_setprio(1);
#pragma unroll
      for (int ks = 0; ks < 2; ++ks)
#pragma unroll
        for (int mf = 0; mf < 4; ++mf)
          acc[mf][3] = __builtin_amdgcn_mfma_f32_16x16x32_bf16(a[mf][ks], b3[ks],
                                                               acc[mf][3], 0, 0, 0);
      __builtin_amdgcn_s_setprio(0);
    }
  }

  // Extract class-1000 dot (cb7/wc1, mf=2, acc-q0, lane-group 2) -> pd,
  // then poison it out of the softmax stats.
  if (cb == 7 && wc == 1 && ((lane >> 4) == 2)) {
#pragma unroll
    for (int nf = 0; nf < 4; ++nf) {
      int r = wr * 64 + nf * 16 + (lane & 15);
      pd[(size_t)rb * 256 + r] = acc[2][nf][0];
      acc[2][nf][0] = -1e30f;
    }
  }

  // Epilogue: per x-row softmax stats over this wave's 64 cls; merge wc
  // halves via LDS.
  __syncthreads();
  float* mm = (float*)lds;
  float* zz = mm + 512;
  float* sv = zz + 512;
#pragma unroll
  for (int nf = 0; nf < 4; ++nf) {
    float m1 = -1e30f;
#pragma unroll
    for (int mf = 0; mf < 4; ++mf)
#pragma unroll
      for (int q = 0; q < 4; ++q) m1 = fmaxf(m1, acc[mf][nf][q]);
    m1 = fmaxf(m1, __shfl_xor(m1, 16));
    m1 = fmaxf(m1, __shfl_xor(m1, 32));
    float z1 = 0.f, s1 = 0.f;
#pragma unroll
    for (int mf = 0; mf < 4; ++mf)
#pragma unroll
      for (int q = 0; q < 4; ++q) {
        float tt = acc[mf][nf][q] - m1;
        float e = expf(tt);
        z1 += e;
        s1 += e * tt;
      }
    z1 += __shfl_xor(z1, 16); z1 += __shfl_xor(z1, 32);
    s1 += __shfl_xor(s1, 16); s1 += __shfl_xor(s1, 32);
    if (lane < 16) {
      int r = wr * 64 + nf * 16 + lane;
      mm[wc * 256 + r] = m1;
      zz[wc * 256 + r] = z1;
      sv[wc * 256 + r] = s1;
    }
  }
  __syncthreads();
  if (tid < 256) {
    float m0 = mm[tid], mA = mm[256 + tid];
    float z0 = zz[tid], zA = zz[256 + tid];
    float s0 = sv[tid], sA = sv[256 + tid];
    float M = fmaxf(m0, mA);
    float e0 = expf(m0 - M), e1 = expf(mA - M);
    float Z = z0 * e0 + zA * e1;
    float S = e0 * (s0 + (m0 - M) * z0) + e1 * (sA + (mA - M) * zA);
    size_t o = (size_t)cb * 8192 + R0 + tid;
    pm[o] = M;
    pz[o] = Z;
    ps[o] = S;
  }

  // Split-K fixup: 8th-arriving chunk-block for this rb merges -> out.
  __threadfence();
  __syncthreads();
  if (tid == 0) lastflag = (atomicAdd(&cnt[rb], 1) == 7) ? 1 : 0;
  __syncthreads();
  if (lastflag) {
    __threadfence();
    if (tid < 256) {
      int row = R0 + tid;
      float mv[8], zv[8], svv[8];
      float M = -1e30f;
#pragma unroll
      for (int c = 0; c < 8; ++c) {
        mv[c] = pm[(size_t)c * 8192 + row];
        zv[c] = pz[(size_t)c * 8192 + row];
        svv[c] = ps[(size_t)c * 8192 + row];
        M = fmaxf(M, mv[c]);
      }
      float Z = 0.f, S = 0.f;
#pragma unroll
      for (int c = 0; c < 8; ++c) {
        float e = expf(mv[c] - M);
        Z += zv[c] * e;
        S += e * (svv[c] + (mv[c] - M) * zv[c]);
      }
      float loss = S / Z - logf(Z);
      out[row] = loss * pd[(size_t)rb * 256 + tid] * rnorm[row] * (1.f / 8192.f);
    }
  }
}

// ---------------------------------------------------------------------------
extern "C" void kernel_launch(void* const* d_in, const int* in_sizes, int n_in,
                              void* d_out, int out_size, void* d_ws, size_t ws_size,
                              hipStream_t stream) {
  (void)in_sizes; (void)n_in; (void)out_size; (void)ws_size;
  const float* x = (const float*)d_in[0];
  const float* W = (const float*)d_in[1];
  const float* b = (const float*)d_in[2];
  float* out = (float*)d_out;
  char* ws = (char*)d_ws;

  unsigned short* Wt = (unsigned short*)(ws + 0);           // 2 MiB
  unsigned short* xbf = (unsigned short*)(ws + 2097152);    // 16 MiB
  float* rnorm = (float*)(ws + 18874368);                   // 32 KiB
  float* s = (float*)(ws + 18907136);                       // 4 KiB
  int* cnt2 = (int*)(ws + 18911232);                        // 4 B
  int* cnt = (int*)(ws + 18911236);                         // 128 B
  float* pm = (float*)(ws + 18915328);                      // 8*8192*4 = 256 KiB
  float* pz = (float*)(ws + 18915328 + 262144);
  float* ps = (float*)(ws + 18915328 + 524288);
  float* pd = (float*)(ws + 18915328 + 786432);             // 32 KiB

  hipMemsetAsync(s, 0, 8192, stream);  // s + cnt2 + cnt
  k01_prep<<<768, 256, 0, stream>>>(W, Wt, x, xbf, rnorm, s, cnt2);
  k3_gemm<<<256, 512, 0, stream>>>(xbf, Wt, b, rnorm, pm, pz, ps, pd, cnt, out);
}

// Round 5
// 65.273 us; speedup vs baseline: 2.2490x; 2.2490x over previous
//
#include <hip/hip_runtime.h>
#include <hip/hip_bf16.h>
#include <cstdint>
#include <cstddef>

typedef __attribute__((ext_vector_type(8))) short bf16x8;
typedef __attribute__((ext_vector_type(4))) float f32x4;

__device__ __forceinline__ unsigned short f2bf(float f) {
  union { float f; unsigned u; } v; v.f = f;
  unsigned r = v.u + 0x7FFFu + ((v.u >> 16) & 1u);
  return (unsigned short)(r >> 16);
}

__device__ __forceinline__ void gload_lds16(const void* g, void* l) {
  __builtin_amdgcn_global_load_lds(
      (const __attribute__((address_space(1))) unsigned int*)g,
      (__attribute__((address_space(3))) unsigned int*)l, 16, 0, 0);
}

// Fence-free cross-block visibility (split-K pattern): relaxed agent-scope
// stores/loads go through the coherence point with NO buffer_wbl2/inv.
__device__ __forceinline__ void st_agent(float* p, float v) {
  __hip_atomic_store(p, v, __ATOMIC_RELAXED, __HIP_MEMORY_SCOPE_AGENT);
}
__device__ __forceinline__ float ld_agent(const float* p) {
  return __hip_atomic_load(p, __ATOMIC_RELAXED, __HIP_MEMORY_SCOPE_AGENT);
}

// ---------------------------------------------------------------------------
// K01 fused: blocks [0,256): W transpose->bf16 Wt[1024cls][1024k] (pad 0,
//            row 1000 reserved for s). blocks [256,768): per-row rnorm,
//            x->bf16, s += xn (device atomics). Last-arriving norm block
//            (fence-free counter protocol) writes bf16(s) into Wt row 1000.
// ---------------------------------------------------------------------------
__global__ __launch_bounds__(256) void k01_prep(const float* __restrict__ W,
                                                unsigned short* __restrict__ Wt,
                                                const float* __restrict__ x,
                                                unsigned short* __restrict__ xbf,
                                                float* __restrict__ rnorm,
                                                float* __restrict__ s,
                                                int* __restrict__ cnt2) {
  __shared__ __align__(16) char sm[16640];
  __shared__ int lf;
  int tid = threadIdx.x;
  if (blockIdx.x < 256) {
    float (*tile)[65] = (float(*)[65])sm;
    int k0 = (blockIdx.x & 15) * 64;
    int c0 = (blockIdx.x >> 4) * 64;
    int tx = tid & 63;
    int ty = tid >> 6;
#pragma unroll
    for (int i = 0; i < 16; ++i) {
      int r = i * 4 + ty;
      int c = c0 + tx;
      tile[r][tx] = (c < 1000) ? W[(size_t)(k0 + r) * 1000 + c] : 0.f;
    }
    __syncthreads();
#pragma unroll
    for (int i = 0; i < 16; ++i) {
      int ct = i * 4 + ty;
      int cg = c0 + ct;
      if (cg != 1000)
        Wt[(size_t)cg * 1024 + (k0 + tx)] = f2bf(tile[tx][ct]);
    }
    return;
  }
  float (*sblk)[1024] = (float(*)[1024])sm;
  int bid = blockIdx.x - 256;
  int wid = tid >> 6, lane = tid & 63;
  float4 sacc[4];
#pragma unroll
  for (int j = 0; j < 4; ++j) sacc[j] = make_float4(0.f, 0.f, 0.f, 0.f);
#pragma unroll
  for (int r = 0; r < 4; ++r) {
    int row = bid * 16 + wid * 4 + r;
    const float4* xr = (const float4*)(x + (size_t)row * 1024);
    float4 v[4];
    float ss = 0.f;
#pragma unroll
    for (int j = 0; j < 4; ++j) {
      v[j] = xr[lane + j * 64];
      ss += v[j].x * v[j].x + v[j].y * v[j].y + v[j].z * v[j].z + v[j].w * v[j].w;
    }
#pragma unroll
    for (int m = 1; m < 64; m <<= 1) ss += __shfl_xor(ss, m);
    float rn = 1.f / fmaxf(sqrtf(ss), 1e-8f);
    if (lane == 0) rnorm[row] = rn;
#pragma unroll
    for (int j = 0; j < 4; ++j) {
      ushort4 hv;
      hv.x = f2bf(v[j].x); hv.y = f2bf(v[j].y);
      hv.z = f2bf(v[j].z); hv.w = f2bf(v[j].w);
      ((ushort4*)(xbf + (size_t)row * 1024))[lane + j * 64] = hv;
      sacc[j].x += v[j].x * rn; sacc[j].y += v[j].y * rn;
      sacc[j].z += v[j].z * rn; sacc[j].w += v[j].w * rn;
    }
  }
#pragma unroll
  for (int j = 0; j < 4; ++j) ((float4*)sblk[wid])[j * 64 + lane] = sacc[j];
  __syncthreads();
  for (int d = tid; d < 1024; d += 256) {
    float t = sblk[0][d] + sblk[1][d] + sblk[2][d] + sblk[3][d];
    atomicAdd(&s[d], t);  // device-scope RMW at coherence point
  }
  // Ensure own RMWs retired, then count. No cache-maintenance fences.
  asm volatile("s_waitcnt vmcnt(0)" ::: "memory");
  __syncthreads();
  if (tid == 0) lf = (atomicAdd(cnt2, 1) == 511) ? 1 : 0;
  __syncthreads();
  if (lf) {
    ushort4 h;
    h.x = f2bf(ld_agent(&s[tid * 4 + 0]));
    h.y = f2bf(ld_agent(&s[tid * 4 + 1]));
    h.z = f2bf(ld_agent(&s[tid * 4 + 2]));
    h.w = f2bf(ld_agent(&s[tid * 4 + 3]));
    ((ushort4*)(Wt + (size_t)1000 * 1024))[tid] = h;  // kernel-boundary flush
  }
}

// ---------------------------------------------------------------------------
// K3: bf16 MFMA GEMM (cls x rows) + fused softmax partials + split-K fixup.
// Block = 128 cls x 256 rows, BK=64; grid 256 = 8 cls-chunks (XCD RR) x 32
// row-blocks; 512 thr (8 waves, 2c x 4r, wave = 64x64). Tri-buffered LDS,
// depth-2 prefetch, counted vmcnt(6); tile-15 peeled behind vmcnt(0) (fixes
// the R3 tail race with no in-loop wait branch). XOR-swizzle via inverse-
// swizzled global source. Class 1000 = dot(x_row, s) -> pd, masked from
// stats. Fence-free fixup: agent-relaxed partial stores + vmcnt(0) +
// relaxed counter; 8th-arriving block per rb merges -> out.
// ---------------------------------------------------------------------------
#define LDSBUF 49152

__global__ __launch_bounds__(512) void k3_gemm(const unsigned short* __restrict__ xbf,
                                               const unsigned short* __restrict__ wt,
                                               const float* __restrict__ bias,
                                               const float* __restrict__ rnorm,
                                               float* __restrict__ pm,
                                               float* __restrict__ pz,
                                               float* __restrict__ ps,
                                               float* __restrict__ pd,
                                               int* __restrict__ cnt,
                                               float* __restrict__ out) {
  __shared__ __align__(16) char lds[147456];
  __shared__ int lastflag;

  int tid = threadIdx.x;
  int lane = tid & 63;
  int wid = tid >> 6;
  int wc = wid & 1;
  int wr = wid >> 1;
  int cb = blockIdx.x & 7;
  int rb = blockIdx.x >> 3;
  int C0 = cb * 128;
  int R0 = rb * 256;

  float bv[4][4];
#pragma unroll
  for (int mf = 0; mf < 4; ++mf)
#pragma unroll
    for (int q = 0; q < 4; ++q) {
      int cls_g = C0 + wc * 64 + mf * 16 + (lane >> 4) * 4 + q;
      bv[mf][q] = (cls_g < 1000) ? bias[cls_g] : ((cls_g == 1000) ? 0.f : -1e30f);
    }
  f32x4 acc[4][4];
#pragma unroll
  for (int mf = 0; mf < 4; ++mf)
#pragma unroll
    for (int nf = 0; nf < 4; ++nf)
#pragma unroll
      for (int q = 0; q < 4; ++q) acc[mf][nf][q] = bv[mf][q];

  const char* gA = (const char*)(wt + (size_t)C0 * 1024);
  const char* gB = (const char*)(xbf + (size_t)R0 * 1024);
  int grow = lane >> 3;
  int gswz = ((lane & 7) ^ grow) << 4;

#define STA(kt, b, r)                                                          \
  gload_lds16(gA + (size_t)((r) * 64 + wid * 8 + grow) * 2048 + (kt) * 128 +   \
                  gswz,                                                        \
              lds + (b) * LDSBUF + (r) * 8192 + wid * 1024)
#define STB(kt, b, r)                                                          \
  gload_lds16(gB + (size_t)((r) * 64 + wid * 8 + grow) * 2048 + (kt) * 128 +   \
                  gswz,                                                        \
              lds + (b) * LDSBUF + 16384 + (r) * 8192 + wid * 1024)

  STA(0, 0, 0); STA(0, 0, 1); STB(0, 0, 0); STB(0, 0, 1); STB(0, 0, 2); STB(0, 0, 3);
  STA(1, 1, 0); STA(1, 1, 1); STB(1, 1, 0); STB(1, 1, 1); STB(1, 1, 2); STB(1, 1, 3);

  int rsw = (lane & 7) << 4;
  int kcol = (lane >> 4) * 16;

  auto ktile = [&](const char* A, const char* B, int nt, int nb, bool pf) {
    if (pf) { STA(nt, nb, 0); STA(nt, nb, 1); }
    bf16x8 a[4][2];
#pragma unroll
    for (int mf = 0; mf < 4; ++mf)
#pragma unroll
      for (int ks = 0; ks < 2; ++ks)
        a[mf][ks] = *(const bf16x8*)(A + (wc * 64 + mf * 16 + (lane & 15)) * 128 +
                                     ((ks * 64 + kcol) ^ rsw));
    {
      bf16x8 b0[2];
#pragma unroll
      for (int ks = 0; ks < 2; ++ks)
        b0[ks] = *(const bf16x8*)(B + (wr * 64 + 0 * 16 + (lane & 15)) * 128 +
                                  ((ks * 64 + kcol) ^ rsw));
      __builtin_amdgcn_s_setprio(1);
#pragma unroll
      for (int ks = 0; ks < 2; ++ks)
#pragma unroll
        for (int mf = 0; mf < 4; ++mf)
          acc[mf][0] = __builtin_amdgcn_mfma_f32_16x16x32_bf16(a[mf][ks], b0[ks],
                                                               acc[mf][0], 0, 0, 0);
      __builtin_amdgcn_s_setprio(0);
    }
    if (pf) { STB(nt, nb, 0); STB(nt, nb, 1); }
    {
      bf16x8 b1[2];
#pragma unroll
      for (int ks = 0; ks < 2; ++ks)
        b1[ks] = *(const bf16x8*)(B + (wr * 64 + 1 * 16 + (lane & 15)) * 128 +
                                  ((ks * 64 + kcol) ^ rsw));
      __builtin_amdgcn_s_setprio(1);
#pragma unroll
      for (int ks = 0; ks < 2; ++ks)
#pragma unroll
        for (int mf = 0; mf < 4; ++mf)
          acc[mf][1] = __builtin_amdgcn_mfma_f32_16x16x32_bf16(a[mf][ks], b1[ks],
                                                               acc[mf][1], 0, 0, 0);
      __builtin_amdgcn_s_setprio(0);
    }
    if (pf) { STB(nt, nb, 2); STB(nt, nb, 3); }
    {
      bf16x8 b2[2];
#pragma unroll
      for (int ks = 0; ks < 2; ++ks)
        b2[ks] = *(const bf16x8*)(B + (wr * 64 + 2 * 16 + (lane & 15)) * 128 +
                                  ((ks * 64 + kcol) ^ rsw));
      __builtin_amdgcn_s_setprio(1);
#pragma unroll
      for (int ks = 0; ks < 2; ++ks)
#pragma unroll
        for (int mf = 0; mf < 4; ++mf)
          acc[mf][2] = __builtin_amdgcn_mfma_f32_16x16x32_bf16(a[mf][ks], b2[ks],
                                                               acc[mf][2], 0, 0, 0);
      __builtin_amdgcn_s_setprio(0);
    }
    {
      bf16x8 b3[2];
#pragma unroll
      for (int ks = 0; ks < 2; ++ks)
        b3[ks] = *(const bf16x8*)(B + (wr * 64 + 3 * 16 + (lane & 15)) * 128 +
                                  ((ks * 64 + kcol) ^ rsw));
      __builtin_amdgcn_s_setprio(1);
#pragma unroll
      for (int ks = 0; ks < 2; ++ks)
#pragma unroll
        for (int mf = 0; mf < 4; ++mf)
          acc[mf][3] = __builtin_amdgcn_mfma_f32_16x16x32_bf16(a[mf][ks], b3[ks],
                                                               acc[mf][3], 0, 0, 0);
      __builtin_amdgcn_s_setprio(0);
    }
  };

  for (int t = 0; t < 15; ++t) {
    asm volatile("s_waitcnt vmcnt(6)" ::: "memory");
    __builtin_amdgcn_s_barrier();
    asm volatile("" ::: "memory");
    const char* A = lds + (t % 3) * LDSBUF;
    ktile(A, A + 16384, t + 2, (t + 2) % 3, t < 14);
  }
  // peeled tile 15: only its own 6 loads outstanding -> full drain
  asm volatile("s_waitcnt vmcnt(0)" ::: "memory");
  __builtin_amdgcn_s_barrier();
  asm volatile("" ::: "memory");
  {
    const char* A = lds + (15 % 3) * LDSBUF;
    ktile(A, A + 16384, 0, 0, false);
  }

  // Extract class-1000 dot -> pd (agent store), mask from stats.
  if (cb == 7 && wc == 1 && ((lane >> 4) == 2)) {
#pragma unroll
    for (int nf = 0; nf < 4; ++nf) {
      int r = wr * 64 + nf * 16 + (lane & 15);
      st_agent(&pd[(size_t)rb * 256 + r], acc[2][nf][0]);
      acc[2][nf][0] = -1e30f;
    }
  }

  __syncthreads();
  float* mm = (float*)lds;
  float* zz = mm + 512;
  float* sv = zz + 512;
#pragma unroll
  for (int nf = 0; nf < 4; ++nf) {
    float m1 = -1e30f;
#pragma unroll
    for (int mf = 0; mf < 4; ++mf)
#pragma unroll
      for (int q = 0; q < 4; ++q) m1 = fmaxf(m1, acc[mf][nf][q]);
    m1 = fmaxf(m1, __shfl_xor(m1, 16));
    m1 = fmaxf(m1, __shfl_xor(m1, 32));
    float z1 = 0.f, s1 = 0.f;
#pragma unroll
    for (int mf = 0; mf < 4; ++mf)
#pragma unroll
      for (int q = 0; q < 4; ++q) {
        float tt = acc[mf][nf][q] - m1;
        float e = expf(tt);
        z1 += e;
        s1 += e * tt;
      }
    z1 += __shfl_xor(z1, 16); z1 += __shfl_xor(z1, 32);
    s1 += __shfl_xor(s1, 16); s1 += __shfl_xor(s1, 32);
    if (lane < 16) {
      int r = wr * 64 + nf * 16 + lane;
      mm[wc * 256 + r] = m1;
      zz[wc * 256 + r] = z1;
      sv[wc * 256 + r] = s1;
    }
  }
  __syncthreads();
  if (tid < 256) {
    float m0 = mm[tid], mA = mm[256 + tid];
    float z0 = zz[tid], zA = zz[256 + tid];
    float s0 = sv[tid], sA = sv[256 + tid];
    float M = fmaxf(m0, mA);
    float e0 = expf(m0 - M), e1 = expf(mA - M);
    float Z = z0 * e0 + zA * e1;
    float S = e0 * (s0 + (m0 - M) * z0) + e1 * (sA + (mA - M) * zA);
    size_t o = (size_t)cb * 8192 + R0 + tid;
    st_agent(&pm[o], M);
    st_agent(&pz[o], Z);
    st_agent(&ps[o], S);
  }

  // Fence-free split-K fixup: own agent-stores retired -> count -> last merges.
  asm volatile("s_waitcnt vmcnt(0)" ::: "memory");
  __syncthreads();
  if (tid == 0) lastflag = (atomicAdd(&cnt[rb], 1) == 7) ? 1 : 0;
  __syncthreads();
  if (lastflag && tid < 256) {
    int row = R0 + tid;
    float mv[8], zv[8], svv[8];
    float M = -1e30f;
#pragma unroll
    for (int c = 0; c < 8; ++c) {
      mv[c] = ld_agent(&pm[(size_t)c * 8192 + row]);
      zv[c] = ld_agent(&pz[(size_t)c * 8192 + row]);
      svv[c] = ld_agent(&ps[(size_t)c * 8192 + row]);
      M = fmaxf(M, mv[c]);
    }
    float Z = 0.f, S = 0.f;
#pragma unroll
    for (int c = 0; c < 8; ++c) {
      float e = expf(mv[c] - M);
      Z += zv[c] * e;
      S += e * (svv[c] + (mv[c] - M) * zv[c]);
    }
    float loss = S / Z - logf(Z);
    float dotv = ld_agent(&pd[(size_t)rb * 256 + tid]);
    out[row] = loss * dotv * rnorm[row] * (1.f / 8192.f);
  }
}

// ---------------------------------------------------------------------------
extern "C" void kernel_launch(void* const* d_in, const int* in_sizes, int n_in,
                              void* d_out, int out_size, void* d_ws, size_t ws_size,
                              hipStream_t stream) {
  (void)in_sizes; (void)n_in; (void)out_size; (void)ws_size;
  const float* x = (const float*)d_in[0];
  const float* W = (const float*)d_in[1];
  const float* b = (const float*)d_in[2];
  float* out = (float*)d_out;
  char* ws = (char*)d_ws;

  unsigned short* Wt = (unsigned short*)(ws + 0);           // 2 MiB
  unsigned short* xbf = (unsigned short*)(ws + 2097152);    // 16 MiB
  float* rnorm = (float*)(ws + 18874368);                   // 32 KiB
  float* s = (float*)(ws + 18907136);                       // 4 KiB
  int* cnt2 = (int*)(ws + 18911232);                        // 4 B
  int* cnt = (int*)(ws + 18911236);                         // 128 B
  float* pm = (float*)(ws + 18915328);                      // 256 KiB
  float* pz = (float*)(ws + 18915328 + 262144);
  float* ps = (float*)(ws + 18915328 + 524288);
  float* pd = (float*)(ws + 18915328 + 786432);             // 32 KiB

  hipMemsetAsync(s, 0, 8192, stream);  // covers s + cnt2 + cnt
  k01_prep<<<768, 256, 0, stream>>>(W, Wt, x, xbf, rnorm, s, cnt2);
  k3_gemm<<<256, 512, 0, stream>>>(xbf, Wt, b, rnorm, pm, pz, ps, pd, cnt, out);
}